// Round 3
// baseline (9144.374 us; speedup 1.0000x reference)
//
#include <hip/hip_runtime.h>
#include <math.h>

#define TT   256   // timesteps
#define HH   64    // hidden
#define G4   256   // 4*H gate columns
#define INw  46    // input size
#define NCLS 8     // classes
#define BT   2     // batch rows per scan block
#define ST   32    // staged timesteps per chunk
#define B2   8     // batch rows per epilogue block

__device__ __forceinline__ float frcp(float x) { return __builtin_amdgcn_rcpf(x); }
__device__ __forceinline__ float sigmoid_f(float x) { return frcp(1.f + __expf(-x)); }
__device__ __forceinline__ float tanh_f(float x) {
    float a = fabsf(x);
    float e = __expf(-2.f * a);
    float r = (1.f - e) * frcp(1.f + e);
    return x >= 0.f ? r : -r;
}
__device__ __forceinline__ float dot4(float4 w, float4 a, float acc) {
    acc = fmaf(w.x, a.x, acc);
    acc = fmaf(w.y, a.y, acc);
    acc = fmaf(w.z, a.z, acc);
    acc = fmaf(w.w, a.w, acc);
    return acc;
}

// ---------------------------------------------------------------------------
// Forward LSTM scan. Block = 2 batch rows, 256 threads (thread j = gate col j).
// grid 1024 -> 4 blocks/CU (16 waves/CU). LDS ~14.8 KB. VGPR capped at 128.
// Per step: h-dependent path = 16 dot4/row; x-projection for step t+1 is
// computed in the cell-update phase (off the recurrent critical path).
// ---------------------------------------------------------------------------
__global__ __launch_bounds__(256, 4) void lstm_fwd_scan(
    const float* __restrict__ x,     // (B,T,46)
    const float* __restrict__ Wih,   // (256,46)
    const float* __restrict__ Whh,   // (256,64)
    const float* __restrict__ bih,   // (256)
    const float* __restrict__ bhh,   // (256)
    float* __restrict__ hf_out)      // (B,64)
{
    __shared__ float x_lds[BT][ST][48];  // padded 46->48 for aligned float4
    __shared__ float h_lds[BT][HH];
    __shared__ float act[BT][G4];

    const int j  = threadIdx.x;
    const int b0 = blockIdx.x * BT;
    const int p  = j >> 6;
    const int l  = j & 63;

    // weights for gate column j in registers
    float4 wih4[12];
#pragma unroll
    for (int ii = 0; ii < 11; ++ii)
        wih4[ii] = make_float4(Wih[j*INw + 4*ii + 0], Wih[j*INw + 4*ii + 1],
                               Wih[j*INw + 4*ii + 2], Wih[j*INw + 4*ii + 3]);
    wih4[11] = make_float4(Wih[j*INw + 44], Wih[j*INw + 45], 0.f, 0.f);

    float4 whh4[16];
#pragma unroll
    for (int ii = 0; ii < 16; ++ii)
        whh4[ii] = make_float4(Whh[j*HH + 4*ii + 0], Whh[j*HH + 4*ii + 1],
                               Whh[j*HH + 4*ii + 2], Whh[j*HH + 4*ii + 3]);

    const float bias = bih[j] + bhh[j];
    const bool  gate_is_tanh = (p == 2);  // wave-uniform: wave 2 = g-gate cols

    if (p < BT) h_lds[p][l] = 0.f;
    float c = 0.f, hcur = 0.f;
    float acc[BT];   // bias + x-projection for the CURRENT step

    for (int t0 = 0; t0 < TT; t0 += ST) {
        // ---- stage x chunk ----
        const float* xsrc = x + (size_t)b0 * TT * INw + (size_t)t0 * INw;
        for (int e = j; e < BT * ST * INw; e += 256) {
            int b = e / (ST * INw);
            int r = e - b * (ST * INw);
            int t = r / INw;
            int i = r - t * INw;
            x_lds[b][t][i] = xsrc[(size_t)b * TT * INw + r];
        }
        for (int e = j; e < BT * ST; e += 256) {
            int b = e / ST, t = e - (e / ST) * ST;
            x_lds[b][t][46] = 0.f;
            x_lds[b][t][47] = 0.f;
        }
        __syncthreads();

        // x-projection for the first step of this chunk
#pragma unroll
        for (int b = 0; b < BT; ++b) acc[b] = bias;
#pragma unroll
        for (int ii = 0; ii < 12; ++ii) {
            float4 w = wih4[ii];
#pragma unroll
            for (int b = 0; b < BT; ++b) {
                float4 a = *(const float4*)&x_lds[b][0][4*ii];
                acc[b] = dot4(w, a, acc[b]);
            }
        }

        for (int ts = 0; ts < ST; ++ts) {
            // ---- h-dependent path: recurrent projection only ----
#pragma unroll
            for (int ii = 0; ii < 16; ++ii) {
                float4 w  = whh4[ii];
                float4 h0 = *(const float4*)&h_lds[0][4*ii];
                float4 h1 = *(const float4*)&h_lds[1][4*ii];
                acc[0] = dot4(w, h0, acc[0]);
                acc[1] = dot4(w, h1, acc[1]);
            }
            float v0, v1;
            if (gate_is_tanh) { v0 = tanh_f(acc[0]);    v1 = tanh_f(acc[1]); }
            else              { v0 = sigmoid_f(acc[0]); v1 = sigmoid_f(acc[1]); }
            act[0][j] = v0;
            act[1][j] = v1;
            __syncthreads();

            // ---- overlap zone: x-projection for NEXT step (all threads) ----
            const int tn = (ts + 1 < ST) ? ts + 1 : ST - 1;  // clamped; chunk
            float accx[BT];                                   // start recomputes
#pragma unroll
            for (int b = 0; b < BT; ++b) accx[b] = bias;
#pragma unroll
            for (int ii = 0; ii < 12; ++ii) {
                float4 w = wih4[ii];
#pragma unroll
                for (int b = 0; b < BT; ++b) {
                    float4 a = *(const float4*)&x_lds[b][tn][4*ii];
                    accx[b] = dot4(w, a, accx[b]);
                }
            }

            // ---- cell/hidden update on waves 0,1 ----
            if (p < BT) {
                float ig = act[p][l];
                float fg = act[p][64  + l];
                float gg = act[p][128 + l];
                float og = act[p][192 + l];
                c    = fmaf(fg, c, ig * gg);
                hcur = og * tanh_f(c);
                h_lds[p][l] = hcur;
            }
            __syncthreads();

#pragma unroll
            for (int b = 0; b < BT; ++b) acc[b] = accx[b];
        }
    }
    if (p < BT) hf_out[(size_t)(b0 + p) * HH + l] = hcur;
}

// ---------------------------------------------------------------------------
// Epilogue: backward dir = ONE LSTM step on x[:,T-1,:] (h0=c0=0, Whh_b unused),
// then FC + softmax.
// ---------------------------------------------------------------------------
__global__ __launch_bounds__(256) void lstm_bwd_fc(
    const float* __restrict__ x,
    const float* __restrict__ Wih,
    const float* __restrict__ bih,
    const float* __restrict__ bhh,
    const float* __restrict__ fcW,
    const float* __restrict__ fcb,
    const float* __restrict__ hf,
    float* __restrict__ out)
{
    __shared__ float xl[B2][48];
    __shared__ float act[B2][G4];
    __shared__ float hbl[B2][HH];

    const int j  = threadIdx.x;
    const int b0 = blockIdx.x * B2;

    for (int e = j; e < B2 * INw; e += 256) {
        int b = e / INw, i = e - b * INw;
        xl[b][i] = x[((size_t)(b0 + b) * TT + (TT - 1)) * INw + i];
    }
    if (j < B2) { xl[j][46] = 0.f; xl[j][47] = 0.f; }
    __syncthreads();

    float4 wih4[12];
#pragma unroll
    for (int ii = 0; ii < 11; ++ii)
        wih4[ii] = make_float4(Wih[j*INw + 4*ii + 0], Wih[j*INw + 4*ii + 1],
                               Wih[j*INw + 4*ii + 2], Wih[j*INw + 4*ii + 3]);
    wih4[11] = make_float4(Wih[j*INw + 44], Wih[j*INw + 45], 0.f, 0.f);
    const float bias = bih[j] + bhh[j];
    const bool  gate_is_tanh = ((j >> 6) == 2);

#pragma unroll
    for (int b = 0; b < B2; ++b) {
        float a = bias;
#pragma unroll
        for (int ii = 0; ii < 12; ++ii) {
            float4 xv = *(const float4*)&xl[b][4*ii];
            a = dot4(wih4[ii], xv, a);
        }
        act[b][j] = gate_is_tanh ? tanh_f(a) : sigmoid_f(a);
    }
    __syncthreads();

    for (int q = j; q < B2 * HH; q += 256) {
        int b = q >> 6, l = q & 63;
        float ig = act[b][l];
        float gg = act[b][128 + l];
        float og = act[b][192 + l];
        hbl[b][l] = og * tanh_f(ig * gg);
    }
    __syncthreads();

    if (j < B2 * NCLS) {
        int b = j >> 3, n = j & 7;
        float a = fcb[n];
        const float* hfr = hf + (size_t)(b0 + b) * HH;
#pragma unroll
        for (int l = 0; l < HH; ++l) {
            a = fmaf(fcW[n * 2 * HH + l],      hfr[l],    a);
            a = fmaf(fcW[n * 2 * HH + HH + l], hbl[b][l], a);
        }
        float m = a;
        m = fmaxf(m, __shfl_xor(m, 1, 8));
        m = fmaxf(m, __shfl_xor(m, 2, 8));
        m = fmaxf(m, __shfl_xor(m, 4, 8));
        float e = __expf(a - m);
        float s = e;
        s += __shfl_xor(s, 1, 8);
        s += __shfl_xor(s, 2, 8);
        s += __shfl_xor(s, 4, 8);
        out[(size_t)(b0 + b) * NCLS + n] = e / s;
    }
}

extern "C" void kernel_launch(void* const* d_in, const int* in_sizes, int n_in,
                              void* d_out, int out_size, void* d_ws, size_t ws_size,
                              hipStream_t stream) {
    const float* x     = (const float*)d_in[0];
    const float* Wih_f = (const float*)d_in[1];
    const float* Whh_f = (const float*)d_in[2];
    const float* bih_f = (const float*)d_in[3];
    const float* bhh_f = (const float*)d_in[4];
    const float* Wih_b = (const float*)d_in[5];
    // d_in[6] = Whh_b: unused — backward dir contributes only its first step (h0=0)
    const float* bih_b = (const float*)d_in[7];
    const float* bhh_b = (const float*)d_in[8];
    const float* fcW   = (const float*)d_in[9];
    const float* fcb   = (const float*)d_in[10];
    float* out = (float*)d_out;
    float* hf  = (float*)d_ws;   // 2048*64 fp32 = 512 KB scratch

    hipLaunchKernelGGL(lstm_fwd_scan, dim3(2048 / BT), dim3(256), 0, stream,
                       x, Wih_f, Whh_f, bih_f, bhh_f, hf);
    hipLaunchKernelGGL(lstm_bwd_fc, dim3(2048 / B2), dim3(256), 0, stream,
                       x, Wih_b, bih_b, bhh_b, fcW, fcb, hf, out);
}

// Round 4
// 1275.806 us; speedup vs baseline: 7.1675x; 7.1675x over previous
//
#include <hip/hip_runtime.h>
#include <math.h>

#define TT   256   // timesteps
#define HH   64    // hidden
#define G4   256   // 4*H gate columns
#define INw  46    // input size
#define NCLS 8     // classes
#define BT   2     // batch rows per scan block
#define ST   32    // staged timesteps per chunk
#define B2   8     // batch rows per epilogue block

__device__ __forceinline__ float frcp(float x) { return __builtin_amdgcn_rcpf(x); }
__device__ __forceinline__ float sigmoid_f(float x) { return frcp(1.f + __expf(-x)); }
__device__ __forceinline__ float tanh_f(float x) {
    float a = fabsf(x);
    float e = __expf(-2.f * a);
    float r = (1.f - e) * frcp(1.f + e);
    return x >= 0.f ? r : -r;
}
__device__ __forceinline__ float dot4(float4 w, float4 a, float acc) {
    acc = fmaf(w.x, a.x, acc);
    acc = fmaf(w.y, a.y, acc);
    acc = fmaf(w.z, a.z, acc);
    acc = fmaf(w.w, a.w, acc);
    return acc;
}

// ---------------------------------------------------------------------------
// Forward LSTM scan, ONE barrier per timestep.
// Block = 2 batch rows, 256 threads (thread j = gate column j, wave w = gate
// type w). Cell update is computed redundantly by ALL waves (c replicated in
// registers); each wave keeps a private h copy in LDS -> no 2nd barrier.
// Gate exchange uses a parity-double-buffered act[] so the single barrier
// (act write -> act read) is the only cross-wave sync per step.
// NOTE: do NOT force an occupancy bucket — R3 showed __launch_bounds__(256,4)
// spills the 112 weight VGPRs to scratch (26 GB of HBM traffic).
// ---------------------------------------------------------------------------
__global__ __launch_bounds__(256, 2) void lstm_fwd_scan(
    const float* __restrict__ x,     // (B,T,46)
    const float* __restrict__ Wih,   // (256,46)
    const float* __restrict__ Whh,   // (256,64)
    const float* __restrict__ bih,   // (256)
    const float* __restrict__ bhh,   // (256)
    float* __restrict__ hf_out)      // (B,64)
{
    __shared__ float x_lds[BT][ST][48];     // 12 KB, padded 46->48
    __shared__ float h_lds[4][BT][HH];      // 2 KB, per-wave private copies
    __shared__ float act[2][BT][G4];        // 4 KB, parity double-buffered

    const int j  = threadIdx.x;
    const int w  = j >> 6;     // wave id == gate type of this thread's column
    const int l  = j & 63;
    const int b0 = blockIdx.x * BT;

    // weights for gate column j in registers
    float4 wih4[12];
#pragma unroll
    for (int ii = 0; ii < 11; ++ii)
        wih4[ii] = make_float4(Wih[j*INw + 4*ii + 0], Wih[j*INw + 4*ii + 1],
                               Wih[j*INw + 4*ii + 2], Wih[j*INw + 4*ii + 3]);
    wih4[11] = make_float4(Wih[j*INw + 44], Wih[j*INw + 45], 0.f, 0.f);

    float4 whh4[16];
#pragma unroll
    for (int ii = 0; ii < 16; ++ii)
        whh4[ii] = make_float4(Whh[j*HH + 4*ii + 0], Whh[j*HH + 4*ii + 1],
                               Whh[j*HH + 4*ii + 2], Whh[j*HH + 4*ii + 3]);

    const float bias = bih[j] + bhh[j];
    const bool  gate_is_tanh = (w == 2);   // wave-uniform

    h_lds[w][0][l] = 0.f;                  // wave-private, no sync needed
    h_lds[w][1][l] = 0.f;
    float c0 = 0.f, c1 = 0.f, h0r = 0.f, h1r = 0.f;
    float xpacc0, xpacc1;

    for (int t0 = 0; t0 < TT; t0 += ST) {
        __syncthreads();   // all waves done reading previous x_lds chunk
        const float* xsrc = x + (size_t)b0 * TT * INw + (size_t)t0 * INw;
        for (int e = j; e < BT * ST * INw; e += 256) {
            int b = e / (ST * INw);
            int r = e - b * (ST * INw);
            int t = r / INw;
            int i = r - t * INw;
            x_lds[b][t][i] = xsrc[(size_t)b * TT * INw + r];
        }
        for (int e = j; e < BT * ST; e += 256) {
            int b = e / ST, t = e - (e / ST) * ST;
            x_lds[b][t][46] = 0.f;
            x_lds[b][t][47] = 0.f;
        }
        __syncthreads();

        // x-projection for first step of this chunk
        xpacc0 = bias; xpacc1 = bias;
#pragma unroll
        for (int ii = 0; ii < 12; ++ii) {
            float4 wv = wih4[ii];
            xpacc0 = dot4(wv, *(const float4*)&x_lds[0][0][4*ii], xpacc0);
            xpacc1 = dot4(wv, *(const float4*)&x_lds[1][0][4*ii], xpacc1);
        }

        for (int ts = 0; ts < ST; ++ts) {
            // ---- h-dependent path: recurrent projection (wave-private h) ----
            float a0 = xpacc0, a1 = xpacc1;
#pragma unroll
            for (int ii = 0; ii < 16; ++ii) {
                float4 wv = whh4[ii];
                a0 = dot4(wv, *(const float4*)&h_lds[w][0][4*ii], a0);
                a1 = dot4(wv, *(const float4*)&h_lds[w][1][4*ii], a1);
            }
            float v0, v1;
            if (gate_is_tanh) { v0 = tanh_f(a0);    v1 = tanh_f(a1); }
            else              { v0 = sigmoid_f(a0); v1 = sigmoid_f(a1); }
            float (*ab)[G4] = act[ts & 1];
            ab[0][j] = v0;
            ab[1][j] = v1;
            __syncthreads();   // THE one barrier per step

            // ---- replicated cell update (all waves, identical results) ----
            float ig0 = ab[0][l],       fg0 = ab[0][64 + l];
            float gg0 = ab[0][128 + l], og0 = ab[0][192 + l];
            float ig1 = ab[1][l],       fg1 = ab[1][64 + l];
            float gg1 = ab[1][128 + l], og1 = ab[1][192 + l];
            c0  = fmaf(fg0, c0, ig0 * gg0);
            c1  = fmaf(fg1, c1, ig1 * gg1);
            h0r = og0 * tanh_f(c0);
            h1r = og1 * tanh_f(c1);
            h_lds[w][0][l] = h0r;      // wave-private: no barrier needed
            h_lds[w][1][l] = h1r;

            // ---- x-projection for NEXT step (off critical path) ----
            const int tn = (ts + 1 < ST) ? ts + 1 : ST - 1;  // clamped
            xpacc0 = bias; xpacc1 = bias;
#pragma unroll
            for (int ii = 0; ii < 12; ++ii) {
                float4 wv = wih4[ii];
                xpacc0 = dot4(wv, *(const float4*)&x_lds[0][tn][4*ii], xpacc0);
                xpacc1 = dot4(wv, *(const float4*)&x_lds[1][tn][4*ii], xpacc1);
            }
        }
    }
    if (w < BT) {
        float hv = (w == 0) ? h0r : h1r;
        hf_out[(size_t)(b0 + w) * HH + l] = hv;
    }
}

// ---------------------------------------------------------------------------
// Epilogue: backward dir = ONE LSTM step on x[:,T-1,:] (h0=c0=0, Whh_b unused),
// then FC + softmax.
// ---------------------------------------------------------------------------
__global__ __launch_bounds__(256) void lstm_bwd_fc(
    const float* __restrict__ x,
    const float* __restrict__ Wih,
    const float* __restrict__ bih,
    const float* __restrict__ bhh,
    const float* __restrict__ fcW,
    const float* __restrict__ fcb,
    const float* __restrict__ hf,
    float* __restrict__ out)
{
    __shared__ float xl[B2][48];
    __shared__ float act[B2][G4];
    __shared__ float hbl[B2][HH];

    const int j  = threadIdx.x;
    const int b0 = blockIdx.x * B2;

    for (int e = j; e < B2 * INw; e += 256) {
        int b = e / INw, i = e - b * INw;
        xl[b][i] = x[((size_t)(b0 + b) * TT + (TT - 1)) * INw + i];
    }
    if (j < B2) { xl[j][46] = 0.f; xl[j][47] = 0.f; }
    __syncthreads();

    float4 wih4[12];
#pragma unroll
    for (int ii = 0; ii < 11; ++ii)
        wih4[ii] = make_float4(Wih[j*INw + 4*ii + 0], Wih[j*INw + 4*ii + 1],
                               Wih[j*INw + 4*ii + 2], Wih[j*INw + 4*ii + 3]);
    wih4[11] = make_float4(Wih[j*INw + 44], Wih[j*INw + 45], 0.f, 0.f);
    const float bias = bih[j] + bhh[j];
    const bool  gate_is_tanh = ((j >> 6) == 2);

#pragma unroll
    for (int b = 0; b < B2; ++b) {
        float a = bias;
#pragma unroll
        for (int ii = 0; ii < 12; ++ii) {
            float4 xv = *(const float4*)&xl[b][4*ii];
            a = dot4(wih4[ii], xv, a);
        }
        act[b][j] = gate_is_tanh ? tanh_f(a) : sigmoid_f(a);
    }
    __syncthreads();

    for (int q = j; q < B2 * HH; q += 256) {
        int b = q >> 6, l = q & 63;
        float ig = act[b][l];
        float gg = act[b][128 + l];
        float og = act[b][192 + l];
        hbl[b][l] = og * tanh_f(ig * gg);
    }
    __syncthreads();

    if (j < B2 * NCLS) {
        int b = j >> 3, n = j & 7;
        float a = fcb[n];
        const float* hfr = hf + (size_t)(b0 + b) * HH;
#pragma unroll
        for (int l = 0; l < HH; ++l) {
            a = fmaf(fcW[n * 2 * HH + l],      hfr[l],    a);
            a = fmaf(fcW[n * 2 * HH + HH + l], hbl[b][l], a);
        }
        float m = a;
        m = fmaxf(m, __shfl_xor(m, 1, 8));
        m = fmaxf(m, __shfl_xor(m, 2, 8));
        m = fmaxf(m, __shfl_xor(m, 4, 8));
        float e = __expf(a - m);
        float s = e;
        s += __shfl_xor(s, 1, 8);
        s += __shfl_xor(s, 2, 8);
        s += __shfl_xor(s, 4, 8);
        out[(size_t)(b0 + b) * NCLS + n] = e / s;
    }
}

extern "C" void kernel_launch(void* const* d_in, const int* in_sizes, int n_in,
                              void* d_out, int out_size, void* d_ws, size_t ws_size,
                              hipStream_t stream) {
    const float* x     = (const float*)d_in[0];
    const float* Wih_f = (const float*)d_in[1];
    const float* Whh_f = (const float*)d_in[2];
    const float* bih_f = (const float*)d_in[3];
    const float* bhh_f = (const float*)d_in[4];
    const float* Wih_b = (const float*)d_in[5];
    // d_in[6] = Whh_b: unused — backward dir contributes only its first step (h0=0)
    const float* bih_b = (const float*)d_in[7];
    const float* bhh_b = (const float*)d_in[8];
    const float* fcW   = (const float*)d_in[9];
    const float* fcb   = (const float*)d_in[10];
    float* out = (float*)d_out;
    float* hf  = (float*)d_ws;   // 2048*64 fp32 = 512 KB scratch

    hipLaunchKernelGGL(lstm_fwd_scan, dim3(2048 / BT), dim3(256), 0, stream,
                       x, Wih_f, Whh_f, bih_f, bhh_f, hf);
    hipLaunchKernelGGL(lstm_bwd_fc, dim3(2048 / B2), dim3(256), 0, stream,
                       x, Wih_b, bih_b, bhh_b, fcW, fcb, hf, out);
}

// Round 5
// 393.486 us; speedup vs baseline: 23.2394x; 3.2423x over previous
//
#include <hip/hip_runtime.h>
#include <math.h>

#define TT   256   // timesteps
#define HH   64    // hidden
#define INw  46    // input size
#define NCLS 8     // classes
#define BB   8     // batch rows per scan block
#define B2   8     // batch rows per epilogue block
#define HP   76    // padded row stride (u32 words) for h LDS tile

typedef __attribute__((ext_vector_type(8))) short  short8v;  // 8 bf16
typedef __attribute__((ext_vector_type(4))) float  float4v;
typedef __attribute__((ext_vector_type(4))) unsigned int uint4v;

__device__ __forceinline__ float frcp(float x) { return __builtin_amdgcn_rcpf(x); }
__device__ __forceinline__ float sigmoid_f(float x) { return frcp(1.f + __expf(-x)); }
__device__ __forceinline__ float tanh_f(float x) {
    float a = fabsf(x);
    float e = __expf(-2.f * a);
    float r = (1.f - e) * frcp(1.f + e);
    return x >= 0.f ? r : -r;
}
__device__ __forceinline__ float dot4(float4 w, float4 a, float acc) {
    acc = fmaf(w.x, a.x, acc);
    acc = fmaf(w.y, a.y, acc);
    acc = fmaf(w.z, a.z, acc);
    acc = fmaf(w.w, a.w, acc);
    return acc;
}

// float -> bf16 round-to-nearest-even
__device__ __forceinline__ unsigned short f2bf(float f) {
    unsigned int u = __float_as_uint(f);
    unsigned int r = u + 0x7FFFu + ((u >> 16) & 1u);
    return (unsigned short)(r >> 16);
}
__device__ __forceinline__ float bf2f(unsigned short h) {
    return __uint_as_float(((unsigned int)h) << 16);
}
// split v ~= hi + lo (two bf16, ~17 mantissa bits combined)
__device__ __forceinline__ void split8(const float v[8], short8v& hi, short8v& lo) {
#pragma unroll
    for (int e = 0; e < 8; ++e) {
        unsigned short h = f2bf(v[e]);
        hi[e] = (short)h;
        lo[e] = (short)f2bf(v[e] - bf2f(h));
    }
}

#define MFMA16(A,B,C) __builtin_amdgcn_mfma_f32_16x16x32_bf16((A),(B),(C),0,0,0)

// ---------------------------------------------------------------------------
// MFMA forward LSTM scan. 256 blocks x 8 batch rows, 4 waves/block.
// Wave w owns gate tiles at cols {16w, 64+16w, 128+16w, 192+16w} -> each lane's
// i/f/g/o gates share (row, unit): cell update fully in-lane.
// h crosses steps via one packed (bf16hi|bf16lo) LDS tile, parity dbuf,
// ONE barrier per step. Split-bf16 MFMA for fp32-class accuracy.
// NOTE (R3 lesson): never force an occupancy bucket; needs ~220 VGPR.
// ---------------------------------------------------------------------------
__global__ __launch_bounds__(256, 1) void lstm_fwd_mfma(
    const float* __restrict__ x,     // (B,T,46)
    const float* __restrict__ Wih,   // (256,46)
    const float* __restrict__ Whh,   // (256,64)
    const float* __restrict__ bih,   // (256)
    const float* __restrict__ bhh,   // (256)
    float* __restrict__ hf_out)      // (B,64)
{
    __shared__ unsigned int hbuf[2][16][HP];   // packed h: hi | lo<<16

    const int j   = threadIdx.x;
    const int w   = j >> 6;        // wave id = gate-tile column group
    const int l   = j & 63;
    const int g   = l >> 4;        // k-group within fragment
    const int c16 = l & 15;        // col within 16-wide tile / A row
    const int b0  = blockIdx.x * BB;
    const int u   = 16 * w + c16;  // hidden unit owned by this lane

    // ---- weight fragments in registers (B operand: B[k][n] = W[n][k]) ----
    short8v whh_h[4][2], whh_l[4][2], wih_h[4][2], wih_l[4][2];
    float bias[4];
#pragma unroll
    for (int q = 0; q < 4; ++q) {
        const int n = 64 * q + u;
        bias[q] = bih[n] + bhh[n];
#pragma unroll
        for (int s = 0; s < 2; ++s) {
            float vh[8], vi[8];
#pragma unroll
            for (int e = 0; e < 8; ++e) {
                const int k = 32 * s + 8 * g + e;
                vh[e] = Whh[n * HH + k];
                const int kc = (k < INw) ? k : 0;
                const float t = Wih[n * INw + kc];
                vi[e] = (k < INw) ? t : 0.f;
            }
            split8(vh, whh_h[q][s], whh_l[q][s]);
            split8(vi, wih_h[q][s], wih_l[q][s]);
        }
    }

    // ---- init h buffers (h0 = 0) ----
    for (int idx = j; idx < 2 * 16 * HP; idx += 256)
        ((unsigned int*)hbuf)[idx] = 0u;

    float cst[4]  = {0.f, 0.f, 0.f, 0.f};
    float hnew[4] = {0.f, 0.f, 0.f, 0.f};

    // ---- x stream: lane loads x[row][k] for k = 8g..8g+7 (s=0) and
    //      k = 32+8g..+7 (s=1, masked at k>=46). Rows 8..15 duplicate 0..7.
    const int xrow = c16 & 7;
    const float* prow = x + ((size_t)(b0 + xrow) * TT) * INw;
    const float* pc = prow;
    float xa[8], xb[8];
#pragma unroll
    for (int e = 0; e < 8; ++e) xa[e] = pc[8 * g + e];
#pragma unroll
    for (int e = 0; e < 8; ++e) {
        const int k = 32 + 8 * g + e;
        const float v = pc[(k < INw) ? k : 0];
        xb[e] = (k < INw) ? v : 0.f;
    }
    __syncthreads();

    for (int t = 0; t < TT; ++t) {
        // convert this step's x to A fragments
        short8v axh0, axl0, axh1, axl1;
        split8(xa, axh0, axl0);
        split8(xb, axh1, axl1);

        // read A_h fragments (written last step, other parity buffer)
        const unsigned int* hr = &hbuf[(t + 1) & 1][0][0];
        const uint4v ha0 = *(const uint4v*)(hr + c16 * HP + 8 * g);
        const uint4v ha1 = *(const uint4v*)(hr + c16 * HP + 8 * g + 4);
        const uint4v hb0 = *(const uint4v*)(hr + c16 * HP + 32 + 8 * g);
        const uint4v hb1 = *(const uint4v*)(hr + c16 * HP + 32 + 8 * g + 4);
        short8v ahh0, ahl0, ahh1, ahl1;
#pragma unroll
        for (int e = 0; e < 4; ++e) {
            ahh0[e]     = (short)(ha0[e] & 0xFFFFu); ahl0[e]     = (short)(ha0[e] >> 16);
            ahh0[4 + e] = (short)(ha1[e] & 0xFFFFu); ahl0[4 + e] = (short)(ha1[e] >> 16);
            ahh1[e]     = (short)(hb0[e] & 0xFFFFu); ahl1[e]     = (short)(hb0[e] >> 16);
            ahh1[4 + e] = (short)(hb1[e] & 0xFFFFu); ahl1[4 + e] = (short)(hb1[e] >> 16);
        }

        // prefetch next step's x (safe clamp on last iter; values unused)
        pc += INw;
        const float* pl = (t == TT - 1) ? prow : pc;
#pragma unroll
        for (int e = 0; e < 8; ++e) xa[e] = pl[8 * g + e];
#pragma unroll
        for (int e = 0; e < 8; ++e) {
            const int k = 32 + 8 * g + e;
            const float v = pl[(k < INw) ? k : 0];
            xb[e] = (k < INw) ? v : 0.f;
        }

        // ---- 48 MFMA: z = x*Wih^T + h*Whh^T (split-bf16, 12 per gate tile)
        float4v C[4];
        const float4v z4 = {0.f, 0.f, 0.f, 0.f};
#pragma unroll
        for (int q = 0; q < 4; ++q) C[q] = z4;
#pragma unroll
        for (int q = 0; q < 4; ++q) {
            C[q] = MFMA16(axh0, wih_h[q][0], C[q]);
            C[q] = MFMA16(axh1, wih_h[q][1], C[q]);
            C[q] = MFMA16(ahh0, whh_h[q][0], C[q]);
            C[q] = MFMA16(ahh1, whh_h[q][1], C[q]);
            C[q] = MFMA16(axh0, wih_l[q][0], C[q]);
            C[q] = MFMA16(axh1, wih_l[q][1], C[q]);
            C[q] = MFMA16(axl0, wih_h[q][0], C[q]);
            C[q] = MFMA16(axl1, wih_h[q][1], C[q]);
            C[q] = MFMA16(ahh0, whh_l[q][0], C[q]);
            C[q] = MFMA16(ahh1, whh_l[q][1], C[q]);
            C[q] = MFMA16(ahl0, whh_h[q][0], C[q]);
            C[q] = MFMA16(ahl1, whh_h[q][1], C[q]);
        }

        // ---- gates + cell update (in-lane; D row = 4g+r, col = u) ----
#pragma unroll
        for (int r = 0; r < 4; ++r) {
            const float ig = sigmoid_f(C[0][r] + bias[0]);
            const float fg = sigmoid_f(C[1][r] + bias[1]);
            const float gg = tanh_f   (C[2][r] + bias[2]);
            const float og = sigmoid_f(C[3][r] + bias[3]);
            cst[r]  = fmaf(fg, cst[r], ig * gg);
            hnew[r] = og * tanh_f(cst[r]);
        }

        // ---- pack h (hi|lo) and write to this step's parity buffer ----
        unsigned int* hw = &hbuf[t & 1][0][0];
#pragma unroll
        for (int r = 0; r < 4; ++r) {
            const unsigned short hh = f2bf(hnew[r]);
            const unsigned short ll = f2bf(hnew[r] - bf2f(hh));
            hw[(4 * g + r) * HP + u] = (unsigned int)hh | ((unsigned int)ll << 16);
        }
        __syncthreads();
    }

    // rows 0..7 are the real batch rows (lanes with g<2)
    if (g < 2) {
#pragma unroll
        for (int r = 0; r < 4; ++r)
            hf_out[(size_t)(b0 + 4 * g + r) * HH + u] = hnew[r];
    }
}

// ---------------------------------------------------------------------------
// Epilogue: backward dir = ONE LSTM step on x[:,T-1,:] (h0=c0=0, Whh_b unused),
// then FC + softmax.
// ---------------------------------------------------------------------------
__global__ __launch_bounds__(256) void lstm_bwd_fc(
    const float* __restrict__ x,
    const float* __restrict__ Wih,
    const float* __restrict__ bih,
    const float* __restrict__ bhh,
    const float* __restrict__ fcW,
    const float* __restrict__ fcb,
    const float* __restrict__ hf,
    float* __restrict__ out)
{
    __shared__ float xl[B2][48];
    __shared__ float act[B2][256];
    __shared__ float hbl[B2][HH];

    const int j  = threadIdx.x;
    const int b0 = blockIdx.x * B2;

    for (int e = j; e < B2 * INw; e += 256) {
        int b = e / INw, i = e - b * INw;
        xl[b][i] = x[((size_t)(b0 + b) * TT + (TT - 1)) * INw + i];
    }
    if (j < B2) { xl[j][46] = 0.f; xl[j][47] = 0.f; }
    __syncthreads();

    float4 wih4[12];
#pragma unroll
    for (int ii = 0; ii < 11; ++ii)
        wih4[ii] = make_float4(Wih[j*INw + 4*ii + 0], Wih[j*INw + 4*ii + 1],
                               Wih[j*INw + 4*ii + 2], Wih[j*INw + 4*ii + 3]);
    wih4[11] = make_float4(Wih[j*INw + 44], Wih[j*INw + 45], 0.f, 0.f);
    const float bias = bih[j] + bhh[j];
    const bool  gate_is_tanh = ((j >> 6) == 2);

#pragma unroll
    for (int b = 0; b < B2; ++b) {
        float a = bias;
#pragma unroll
        for (int ii = 0; ii < 12; ++ii) {
            float4 xv = *(const float4*)&xl[b][4*ii];
            a = dot4(wih4[ii], xv, a);
        }
        act[b][j] = gate_is_tanh ? tanh_f(a) : sigmoid_f(a);
    }
    __syncthreads();

    for (int q = j; q < B2 * HH; q += 256) {
        int b = q >> 6, l = q & 63;
        float ig = act[b][l];
        float gg = act[b][128 + l];
        float og = act[b][192 + l];
        hbl[b][l] = og * tanh_f(ig * gg);
    }
    __syncthreads();

    if (j < B2 * NCLS) {
        int b = j >> 3, n = j & 7;
        float a = fcb[n];
        const float* hfr = hf + (size_t)(b0 + b) * HH;
#pragma unroll
        for (int l = 0; l < HH; ++l) {
            a = fmaf(fcW[n * 2 * HH + l],      hfr[l],    a);
            a = fmaf(fcW[n * 2 * HH + HH + l], hbl[b][l], a);
        }
        float m = a;
        m = fmaxf(m, __shfl_xor(m, 1, 8));
        m = fmaxf(m, __shfl_xor(m, 2, 8));
        m = fmaxf(m, __shfl_xor(m, 4, 8));
        float e = __expf(a - m);
        float s = e;
        s += __shfl_xor(s, 1, 8);
        s += __shfl_xor(s, 2, 8);
        s += __shfl_xor(s, 4, 8);
        out[(size_t)(b0 + b) * NCLS + n] = e / s;
    }
}

extern "C" void kernel_launch(void* const* d_in, const int* in_sizes, int n_in,
                              void* d_out, int out_size, void* d_ws, size_t ws_size,
                              hipStream_t stream) {
    const float* x     = (const float*)d_in[0];
    const float* Wih_f = (const float*)d_in[1];
    const float* Whh_f = (const float*)d_in[2];
    const float* bih_f = (const float*)d_in[3];
    const float* bhh_f = (const float*)d_in[4];
    const float* Wih_b = (const float*)d_in[5];
    // d_in[6] = Whh_b: unused — backward dir contributes only its first step (h0=0)
    const float* bih_b = (const float*)d_in[7];
    const float* bhh_b = (const float*)d_in[8];
    const float* fcW   = (const float*)d_in[9];
    const float* fcb   = (const float*)d_in[10];
    float* out = (float*)d_out;
    float* hf  = (float*)d_ws;   // 2048*64 fp32 = 512 KB scratch

    hipLaunchKernelGGL(lstm_fwd_mfma, dim3(2048 / BB), dim3(256), 0, stream,
                       x, Wih_f, Whh_f, bih_f, bhh_f, hf);
    hipLaunchKernelGGL(lstm_bwd_fc, dim3(2048 / B2), dim3(256), 0, stream,
                       x, Wih_b, bih_b, bhh_b, fcW, fcb, hf, out);
}

// Round 6
// 318.257 us; speedup vs baseline: 28.7327x; 1.2364x over previous
//
#include <hip/hip_runtime.h>
#include <math.h>

#define TT   256   // timesteps
#define HH   64    // hidden
#define INw  46    // input size
#define NCLS 8     // classes
#define BB   8     // batch rows per scan block
#define B2   8     // batch rows per epilogue block
#define CH   16    // staged timesteps per chunk
#define XS   72    // padded k-stride (elements) for bf16 LDS tiles (144B, 16B-aligned, rows spread over banks)

typedef __attribute__((ext_vector_type(8))) short  short8v;  // 8 bf16
typedef __attribute__((ext_vector_type(4))) float  float4v;

__device__ __forceinline__ float frcp(float x) { return __builtin_amdgcn_rcpf(x); }
__device__ __forceinline__ float sigmoid_f(float x) { return frcp(1.f + __expf(-x)); }
__device__ __forceinline__ float tanh_f(float x) {
    float a = fabsf(x);
    float e = __expf(-2.f * a);
    float r = (1.f - e) * frcp(1.f + e);
    return x >= 0.f ? r : -r;
}
__device__ __forceinline__ float dot4(float4 w, float4 a, float acc) {
    acc = fmaf(w.x, a.x, acc);
    acc = fmaf(w.y, a.y, acc);
    acc = fmaf(w.z, a.z, acc);
    acc = fmaf(w.w, a.w, acc);
    return acc;
}

// float -> bf16 round-to-nearest-even
__device__ __forceinline__ unsigned short f2bf(float f) {
    unsigned int u = __float_as_uint(f);
    unsigned int r = u + 0x7FFFu + ((u >> 16) & 1u);
    return (unsigned short)(r >> 16);
}
__device__ __forceinline__ float bf2f(unsigned short h) {
    return __uint_as_float(((unsigned int)h) << 16);
}
__device__ __forceinline__ void split8(const float v[8], short8v& hi, short8v& lo) {
#pragma unroll
    for (int e = 0; e < 8; ++e) {
        unsigned short h = f2bf(v[e]);
        hi[e] = (short)h;
        lo[e] = (short)f2bf(v[e] - bf2f(h));
    }
}

#define MFMA16(A,B,C) __builtin_amdgcn_mfma_f32_16x16x32_bf16((A),(B),(C),0,0,0)

// ---------------------------------------------------------------------------
// MFMA forward LSTM scan. 256 blocks x 8 batch rows, 4 waves/block.
// Wave w owns gate tiles at cols {16w, 64+16w, 128+16w, 192+16w} -> each
// lane's i/f/g/o share (row, unit): cell update fully in-lane.
// x is pre-split to bf16 hi/lo in LDS once per 16-step chunk; h crosses steps
// via separate hi/lo bf16 LDS tiles (parity dbuf), fragments read directly
// with ds_read_b128 -> near-zero per-step conversion VALU.
// ONE barrier per step (+1 per chunk). Split-bf16 (3-term) for fp32 accuracy.
// NOTE (R3 lesson): never force a tight occupancy bucket (weight frags ~128
// regs live in the unified VGPR/AGPR file).
// ---------------------------------------------------------------------------
__global__ __launch_bounds__(256, 1) void lstm_fwd_mfma(
    const float* __restrict__ x,     // (B,T,46)
    const float* __restrict__ Wih,   // (256,46)
    const float* __restrict__ Whh,   // (256,64)
    const float* __restrict__ bih,   // (256)
    const float* __restrict__ bhh,   // (256)
    float* __restrict__ hf_out)      // (B,64)
{
    __shared__ short x_hi[CH][BB][XS];   // 18.4 KB
    __shared__ short x_lo[CH][BB][XS];   // 18.4 KB
    __shared__ short h_hi[2][BB][XS];    // 2.3 KB
    __shared__ short h_lo[2][BB][XS];    // 2.3 KB

    const int j    = threadIdx.x;
    const int w    = j >> 6;        // wave id = unit-group
    const int l    = j & 63;
    const int g    = l >> 4;        // k-group within fragment
    const int c16  = l & 15;        // A row / B col within tile
    const int row8 = c16 & 7;       // real batch row (A rows 8..15 alias 0..7)
    const int b0   = blockIdx.x * BB;
    const int u    = 16 * w + c16;  // hidden unit owned by this lane

    // ---- weight fragments in registers (B operand: B[k][n] = W[n][k]) ----
    short8v whh_h[4][2], whh_l[4][2], wih_h[4][2], wih_l[4][2];
    float bias[4];
#pragma unroll
    for (int q = 0; q < 4; ++q) {
        const int n = 64 * q + u;
        bias[q] = bih[n] + bhh[n];
#pragma unroll
        for (int s = 0; s < 2; ++s) {
            float vh[8], vi[8];
#pragma unroll
            for (int e = 0; e < 8; ++e) {
                const int k = 32 * s + 8 * g + e;
                vh[e] = Whh[n * HH + k];
                const int kc = (k < INw) ? k : 0;
                const float t = Wih[n * INw + kc];
                vi[e] = (k < INw) ? t : 0.f;
            }
            split8(vh, whh_h[q][s], whh_l[q][s]);
            split8(vi, wih_h[q][s], wih_l[q][s]);
        }
    }

    // ---- zero LDS: h (both parities) and x (incl. k>=46 pad, zeroed once;
    //      staging only writes k<46, pad stays zero across chunks) ----
    for (int idx = j; idx < 2 * BB * XS; idx += 256) {
        (&h_hi[0][0][0])[idx] = 0;
        (&h_lo[0][0][0])[idx] = 0;
    }
    for (int idx = j; idx < CH * BB * XS; idx += 256) {
        (&x_hi[0][0][0])[idx] = 0;
        (&x_lo[0][0][0])[idx] = 0;
    }

    float cst[4]  = {0.f, 0.f, 0.f, 0.f};
    float hnew[4] = {0.f, 0.f, 0.f, 0.f};
    __syncthreads();

    for (int t0 = 0; t0 < TT; t0 += CH) {
        // ---- stage + pre-split x chunk (prev step barrier covers safety) ----
        for (int e = j; e < BB * CH * INw; e += 256) {
            const int r   = e / (CH * INw);
            const int rem = e - r * (CH * INw);
            const int t   = rem / INw;
            const int k   = rem - t * INw;
            const float v = x[((size_t)(b0 + r) * TT + t0 + t) * INw + k];
            const unsigned short hh = f2bf(v);
            x_hi[t][r][k] = (short)hh;
            x_lo[t][r][k] = (short)f2bf(v - bf2f(hh));
        }
        __syncthreads();

        for (int ts = 0; ts < CH; ++ts) {
            const int t = t0 + ts;

            // ---- fragments: direct b128 reads, zero conversion VALU ----
            const short* hrh = &h_hi[(t + 1) & 1][0][0];
            const short* hrl = &h_lo[(t + 1) & 1][0][0];
            const short8v axh0 = *(const short8v*)&x_hi[ts][row8][8 * g];
            const short8v axh1 = *(const short8v*)&x_hi[ts][row8][32 + 8 * g];
            const short8v axl0 = *(const short8v*)&x_lo[ts][row8][8 * g];
            const short8v axl1 = *(const short8v*)&x_lo[ts][row8][32 + 8 * g];
            const short8v ahh0 = *(const short8v*)(hrh + row8 * XS + 8 * g);
            const short8v ahh1 = *(const short8v*)(hrh + row8 * XS + 32 + 8 * g);
            const short8v ahl0 = *(const short8v*)(hrl + row8 * XS + 8 * g);
            const short8v ahl1 = *(const short8v*)(hrl + row8 * XS + 32 + 8 * g);

            // ---- 48 MFMA: z = x*Wih^T + h*Whh^T (split-bf16, 12/gate) ----
            float4v C[4];
            const float4v z4 = {0.f, 0.f, 0.f, 0.f};
#pragma unroll
            for (int q = 0; q < 4; ++q) C[q] = z4;
#pragma unroll
            for (int q = 0; q < 4; ++q) {
                C[q] = MFMA16(axh0, wih_h[q][0], C[q]);
                C[q] = MFMA16(axh1, wih_h[q][1], C[q]);
                C[q] = MFMA16(ahh0, whh_h[q][0], C[q]);
                C[q] = MFMA16(ahh1, whh_h[q][1], C[q]);
                C[q] = MFMA16(axh0, wih_l[q][0], C[q]);
                C[q] = MFMA16(axh1, wih_l[q][1], C[q]);
                C[q] = MFMA16(axl0, wih_h[q][0], C[q]);
                C[q] = MFMA16(axl1, wih_h[q][1], C[q]);
                C[q] = MFMA16(ahh0, whh_l[q][0], C[q]);
                C[q] = MFMA16(ahh1, whh_l[q][1], C[q]);
                C[q] = MFMA16(ahl0, whh_h[q][0], C[q]);
                C[q] = MFMA16(ahl1, whh_h[q][1], C[q]);
            }

            // ---- gates + cell update (in-lane; D row = 4g+r, col = u) ----
#pragma unroll
            for (int r = 0; r < 4; ++r) {
                const float ig = sigmoid_f(C[0][r] + bias[0]);
                const float fg = sigmoid_f(C[1][r] + bias[1]);
                const float gg = tanh_f   (C[2][r] + bias[2]);
                const float og = sigmoid_f(C[3][r] + bias[3]);
                cst[r]  = fmaf(fg, cst[r], ig * gg);
                hnew[r] = og * tanh_f(cst[r]);
            }

            // ---- write h (rows 0..7 only; split hi/lo, b16 stores) ----
            short* hwh = &h_hi[t & 1][0][0];
            short* hwl = &h_lo[t & 1][0][0];
            if (g < 2) {
#pragma unroll
                for (int r = 0; r < 4; ++r) {
                    const unsigned short hh = f2bf(hnew[r]);
                    hwh[(4 * g + r) * XS + u] = (short)hh;
                    hwl[(4 * g + r) * XS + u] = (short)f2bf(hnew[r] - bf2f(hh));
                }
            }
            __syncthreads();
        }
    }

    if (g < 2) {
#pragma unroll
        for (int r = 0; r < 4; ++r)
            hf_out[(size_t)(b0 + 4 * g + r) * HH + u] = hnew[r];
    }
}

// ---------------------------------------------------------------------------
// Epilogue: backward dir = ONE LSTM step on x[:,T-1,:] (h0=c0=0, Whh_b unused),
// then FC + softmax.
// ---------------------------------------------------------------------------
__global__ __launch_bounds__(256) void lstm_bwd_fc(
    const float* __restrict__ x,
    const float* __restrict__ Wih,
    const float* __restrict__ bih,
    const float* __restrict__ bhh,
    const float* __restrict__ fcW,
    const float* __restrict__ fcb,
    const float* __restrict__ hf,
    float* __restrict__ out)
{
    __shared__ float xl[B2][48];
    __shared__ float act[B2][256];
    __shared__ float hbl[B2][HH];

    const int j  = threadIdx.x;
    const int b0 = blockIdx.x * B2;

    for (int e = j; e < B2 * INw; e += 256) {
        int b = e / INw, i = e - b * INw;
        xl[b][i] = x[((size_t)(b0 + b) * TT + (TT - 1)) * INw + i];
    }
    if (j < B2) { xl[j][46] = 0.f; xl[j][47] = 0.f; }
    __syncthreads();

    float4 wih4[12];
#pragma unroll
    for (int ii = 0; ii < 11; ++ii)
        wih4[ii] = make_float4(Wih[j*INw + 4*ii + 0], Wih[j*INw + 4*ii + 1],
                               Wih[j*INw + 4*ii + 2], Wih[j*INw + 4*ii + 3]);
    wih4[11] = make_float4(Wih[j*INw + 44], Wih[j*INw + 45], 0.f, 0.f);
    const float bias = bih[j] + bhh[j];
    const bool  gate_is_tanh = ((j >> 6) == 2);

#pragma unroll
    for (int b = 0; b < B2; ++b) {
        float a = bias;
#pragma unroll
        for (int ii = 0; ii < 12; ++ii) {
            float4 xv = *(const float4*)&xl[b][4*ii];
            a = dot4(wih4[ii], xv, a);
        }
        act[b][j] = gate_is_tanh ? tanh_f(a) : sigmoid_f(a);
    }
    __syncthreads();

    for (int q = j; q < B2 * HH; q += 256) {
        int b = q >> 6, l = q & 63;
        float ig = act[b][l];
        float gg = act[b][128 + l];
        float og = act[b][192 + l];
        hbl[b][l] = og * tanh_f(ig * gg);
    }
    __syncthreads();

    if (j < B2 * NCLS) {
        int b = j >> 3, n = j & 7;
        float a = fcb[n];
        const float* hfr = hf + (size_t)(b0 + b) * HH;
#pragma unroll
        for (int l = 0; l < HH; ++l) {
            a = fmaf(fcW[n * 2 * HH + l],      hfr[l],    a);
            a = fmaf(fcW[n * 2 * HH + HH + l], hbl[b][l], a);
        }
        float m = a;
        m = fmaxf(m, __shfl_xor(m, 1, 8));
        m = fmaxf(m, __shfl_xor(m, 2, 8));
        m = fmaxf(m, __shfl_xor(m, 4, 8));
        float e = __expf(a - m);
        float s = e;
        s += __shfl_xor(s, 1, 8);
        s += __shfl_xor(s, 2, 8);
        s += __shfl_xor(s, 4, 8);
        out[(size_t)(b0 + b) * NCLS + n] = e / s;
    }
}

extern "C" void kernel_launch(void* const* d_in, const int* in_sizes, int n_in,
                              void* d_out, int out_size, void* d_ws, size_t ws_size,
                              hipStream_t stream) {
    const float* x     = (const float*)d_in[0];
    const float* Wih_f = (const float*)d_in[1];
    const float* Whh_f = (const float*)d_in[2];
    const float* bih_f = (const float*)d_in[3];
    const float* bhh_f = (const float*)d_in[4];
    const float* Wih_b = (const float*)d_in[5];
    // d_in[6] = Whh_b: unused — backward dir contributes only its first step (h0=0)
    const float* bih_b = (const float*)d_in[7];
    const float* bhh_b = (const float*)d_in[8];
    const float* fcW   = (const float*)d_in[9];
    const float* fcb   = (const float*)d_in[10];
    float* out = (float*)d_out;
    float* hf  = (float*)d_ws;   // 2048*64 fp32 = 512 KB scratch

    hipLaunchKernelGGL(lstm_fwd_mfma, dim3(2048 / BB), dim3(256), 0, stream,
                       x, Wih_f, Whh_f, bih_f, bhh_f, hf);
    hipLaunchKernelGGL(lstm_bwd_fc, dim3(2048 / B2), dim3(256), 0, stream,
                       x, Wih_b, bih_b, bhh_b, fcW, fcb, hf, out);
}